// Round 9
// baseline (288.726 us; speedup 1.0000x reference)
//
#include <hip/hip_runtime.h>
#include <math.h>

// Problem constants (from reference)
#define Bb 2
#define Ll 2048
#define Dd 512
#define Hh 8
#define DKq 64
#define NBUCK 16
#define KMAX 64
#define MAX_ITEMS 1280   // exact bound: 16 bh * (64 + 16) chunks of 32

// ---------------------------------------------------------------------------
// Direct global->LDS DMA (gfx950), 16B per lane.  LDS dest = uniform base +
// lane*16 (linear); per-lane GLOBAL address carries any swizzle (m173/m201).
// ---------------------------------------------------------------------------
__device__ __forceinline__ void gl_lds16(const float* g, float* l) {
  __builtin_amdgcn_global_load_lds(
      (const __attribute__((address_space(1))) void*)g,
      (__attribute__((address_space(3))) void*)l, 16, 0, 0);
}

// ---------------------------------------------------------------------------
// Projection GEMM: X(4096x512) @ W(512x512) + b -> (b,h,l,dk) scatter.
// m97-style: 128 thr, BM=64 BN=128 BK=32, 8x8 microtile, grid (4,64,3)=768.
// Staging via global_load_lds into double-buffered LDS, ONE barrier/tile.
//   As [64][32] linear, k4-slot XOR'd with (row>>3) via pre-swizzled global
//   source; compute reads As[row][(kk4^ty)*4] -> 16-lane broadcasts,
//   conflict-free.  Bs [32][128] linear; reads 2-way (free).
// Per-output FMA chain is ascending-k, one fma per k -> bit-identical q/k
// across rounds (LSH sign-critical).  Do not alter math/accumulation order.
// ---------------------------------------------------------------------------
__global__ __launch_bounds__(128) void proj_kernel(
    const float* __restrict__ Xq, const float* __restrict__ Xk, const float* __restrict__ Xv,
    const float* __restrict__ Wq, const float* __restrict__ Wk, const float* __restrict__ Wv,
    const float* __restrict__ bq, const float* __restrict__ bk, const float* __restrict__ bv,
    float* __restrict__ qb, float* __restrict__ kb, float* __restrict__ vb)
{
  const float *X, *W, *bias; float* dst;
  if (blockIdx.z == 0)      { X=Xq; W=Wq; bias=bq; dst=qb; }
  else if (blockIdx.z == 1) { X=Xk; W=Wk; bias=bk; dst=kb; }
  else                      { X=Xv; W=Wv; bias=bv; dst=vb; }
  __shared__ float As[2][64 * 32];    // [buf][m][k4-swizzled], 8 KB each
  __shared__ float Bs[2][32 * 128];   // [buf][k][n], 16 KB each
  const int tid = threadIdx.x;
  const int m0 = blockIdx.y * 64;
  const int n0 = blockIdx.x * 128;
  const int tx = tid & 15, ty = tid >> 4;      // 16 x 8 thread grid
  const int lane = tid & 63, wid = tid >> 6;   // 2 waves

  // Per-lane source pointers (jj = instruction index; swizzle k4 ^= jj).
  const float* aSrc[4];
  #pragma unroll
  for (int j = 0; j < 4; j++) {
    int jj = wid * 4 + j;                      // 8 rows per instruction
    aSrc[j] = X + (size_t)(m0 + 8*jj + (lane >> 3)) * 512 + (((lane & 7) ^ jj) << 2);
  }
  const float* bSrc[8];
  #pragma unroll
  for (int j = 0; j < 8; j++) {
    int jj = wid * 8 + j;                      // 2 k-rows per instruction
    bSrc[j] = W + (size_t)(2*jj + (lane >> 5)) * 512 + n0 + ((lane & 31) << 2);
  }

  // Prologue: stage tile 0 into buffer 0.
  #pragma unroll
  for (int j = 0; j < 4; j++) gl_lds16(aSrc[j],            &As[0][(wid*4+j)*256]);
  #pragma unroll
  for (int j = 0; j < 8; j++) gl_lds16(bSrc[j],            &Bs[0][(wid*8+j)*256]);
  __syncthreads();                              // drains vmcnt

  float acc[8][8] = {};
  for (int t = 0; t < 16; t++) {
    const int cur = t & 1;
    if (t < 15) {                               // stage tile t+1 into other buf
      const int k0 = (t + 1) * 32;
      #pragma unroll
      for (int j = 0; j < 4; j++) gl_lds16(aSrc[j] + k0,              &As[cur^1][(wid*4+j)*256]);
      #pragma unroll
      for (int j = 0; j < 8; j++) gl_lds16(bSrc[j] + (size_t)k0*512,  &Bs[cur^1][(wid*8+j)*256]);
    }
    const float* Ac = &As[cur][0];
    const float* Bc = &Bs[cur][0];
    #pragma unroll
    for (int kk4 = 0; kk4 < 8; kk4++) {
      float4 a[8];
      #pragma unroll
      for (int i = 0; i < 8; i++)
        a[i] = *(const float4*)&Ac[(ty*8 + i)*32 + ((kk4 ^ ty) << 2)];
      #pragma unroll
      for (int s = 0; s < 4; s++) {
        const int kk = kk4*4 + s;
        float4 b0 = *(const float4*)&Bc[kk*128 + tx*4];
        float4 b1 = *(const float4*)&Bc[kk*128 + 64 + tx*4];
        #pragma unroll
        for (int i = 0; i < 8; i++) {
          const float as = (s==0) ? a[i].x : (s==1) ? a[i].y : (s==2) ? a[i].z : a[i].w;
          acc[i][0] += as * b0.x;  acc[i][1] += as * b0.y;
          acc[i][2] += as * b0.z;  acc[i][3] += as * b0.w;
          acc[i][4] += as * b1.x;  acc[i][5] += as * b1.y;
          acc[i][6] += as * b1.z;  acc[i][7] += as * b1.w;
        }
      }
    }
    __syncthreads();   // staging t+1 complete + all reads of cur done
  }

  const int head0 = n0 >> 6;           // two 64-col heads per tile
  const int d0 = tx * 4;
  #pragma unroll
  for (int i = 0; i < 8; i++) {
    int m = m0 + ty*8 + i;
    int b = m >> 11, l = m & 2047;
    float* drow0 = &dst[(((size_t)b*Hh + head0)*Ll + l)*DKq];
    float* drow1 = &dst[(((size_t)b*Hh + head0 + 1)*Ll + l)*DKq];
    #pragma unroll
    for (int j = 0; j < 4; j++) drow0[d0 + j] = acc[i][j]   + bias[n0 + tx*4 + j];
    #pragma unroll
    for (int j = 0; j < 4; j++) drow1[d0 + j] = acc[i][4+j] + bias[n0 + 64 + tx*4 + j];
  }
}

// ---------------------------------------------------------------------------
// LSH hash (unchanged)
// ---------------------------------------------------------------------------
__global__ __launch_bounds__(256) void hash_kernel(
    const float* __restrict__ qb, const float* __restrict__ kb,
    const float* __restrict__ rv, int* __restrict__ qhash, int* __restrict__ khash)
{
  int gwave = (blockIdx.x * blockDim.x + threadIdx.x) >> 6;
  int lane = threadIdx.x & 63;
  const int NR = Bb * Hh * Ll;
  if (gwave >= 2 * NR) return;
  int isK = gwave >= NR;
  int row = isK ? gwave - NR : gwave;
  int h = (row >> 11) & 7;
  const float* src = isK ? kb : qb;
  float x = src[(size_t)row * DKq + lane];
  float r = rv[h * DKq + lane];
  float v = (x > 0.0f) ? r : 0.0f;
  #pragma unroll
  for (int off = 32; off; off >>= 1) v += __shfl_xor(v, off);
  if (lane == 0) {
    float fb = floorf(v * 0.125f);
    int ib = (int)fb;
    int bucket = ib & 15;
    (isK ? khash : qhash)[row] = bucket;
  }
}

// ---------------------------------------------------------------------------
// First <=64 ascending key indices per (b,h,bucket) (unchanged)
// ---------------------------------------------------------------------------
__global__ __launch_bounds__(64) void kcand_kernel(
    const int* __restrict__ khash, int* __restrict__ kcand, int* __restrict__ kcount)
{
  int bh = blockIdx.x >> 4;
  int bucket = blockIdx.x & 15;
  int lane = threadIdx.x;
  const int* kh = &khash[bh * Ll];
  int* cl = &kcand[(size_t)blockIdx.x * KMAX];
  int total = 0;
  for (int c0 = 0; c0 < Ll && total < KMAX; c0 += 64) {
    int hv = kh[c0 + lane];
    unsigned long long m = __ballot(hv == bucket);
    int pre = __popcll(m & ((1ULL << lane) - 1ULL));
    if (hv == bucket && total + pre < KMAX) cl[total + pre] = c0 + lane;
    total += __popcll(m);
  }
  if (lane == 0) kcount[blockIdx.x] = total < KMAX ? total : KMAX;
}

// ---------------------------------------------------------------------------
// Group queries by bucket per (b,h) (unchanged)
// ---------------------------------------------------------------------------
__global__ __launch_bounds__(256) void qlist_kernel(
    const int* __restrict__ qhash, int* __restrict__ qoff, int* __restrict__ qlist)
{
  int bh = blockIdx.x;
  __shared__ int cnt[NBUCK], cur[NBUCK], off[NBUCK + 1];
  if (threadIdx.x < NBUCK) cnt[threadIdx.x] = 0;
  __syncthreads();
  const int* qh = &qhash[bh * Ll];
  for (int l = threadIdx.x; l < Ll; l += 256) atomicAdd(&cnt[qh[l]], 1);
  __syncthreads();
  if (threadIdx.x == 0) {
    int s = 0;
    for (int i = 0; i < NBUCK; i++) { off[i] = s; cur[i] = s; s += cnt[i]; }
    off[NBUCK] = s;
  }
  __syncthreads();
  if (threadIdx.x < NBUCK + 1) qoff[bh * (NBUCK + 1) + threadIdx.x] = off[threadIdx.x];
  for (int l = threadIdx.x; l < Ll; l += 256) {
    int p = atomicAdd(&cur[qh[l]], 1);
    qlist[bh * Ll + p] = l;
  }
}

// ---------------------------------------------------------------------------
// Deterministic worklist: one item per active (bh,bucket,chunk-of-32-queries).
// ---------------------------------------------------------------------------
__global__ __launch_bounds__(256) void worklist_kernel(
    const int* __restrict__ qoff, const int* __restrict__ kcount,
    int4* __restrict__ items, int* __restrict__ nitems)
{
  int t = threadIdx.x;
  int bh = t >> 4, bucket = t & 15;
  int o0 = qoff[bh * 17 + bucket], o1 = qoff[bh * 17 + bucket + 1];
  int cnt = kcount[t];
  int nq = o1 - o0;
  int n = (cnt > 0) ? ((nq + 31) >> 5) : 0;
  __shared__ int sc[256];
  sc[t] = n;
  __syncthreads();
  for (int off = 1; off < 256; off <<= 1) {
    int v = (t >= off) ? sc[t - off] : 0;
    __syncthreads();
    sc[t] += v;
    __syncthreads();
  }
  int start = sc[t] - n;
  for (int i = 0; i < n; i++) {
    int q0 = 32 * i;
    int qn = nq - q0; if (qn > 32) qn = 32;
    items[start + i] = make_int4(t, o0 + q0, qn, cnt);
  }
  if (t == 255) nitems[0] = sc[255];
}

// ---------------------------------------------------------------------------
// LDS fence for same-wave cross-lane LDS dependences (rule #18).
// ---------------------------------------------------------------------------
__device__ __forceinline__ void lds_fence() {
  asm volatile("s_waitcnt lgkmcnt(0)" ::: "memory");
  __builtin_amdgcn_sched_barrier(0);
}

// ---------------------------------------------------------------------------
// Attention: one WAVE per item (<=32 q x <=64 cand x 64 dim).  K rows in
// regs (lane=c), V^T in regs (lane=d), Q via wave-private LDS broadcasts.
// (unchanged from round 4/6/7/8 -- correctness-verified)
// ---------------------------------------------------------------------------
__global__ __launch_bounds__(256, 2) void attn_kernel(
    const float* __restrict__ qb, const float* __restrict__ kb, const float* __restrict__ vb,
    const int* __restrict__ qlist, const int* __restrict__ kcand,
    const int4* __restrict__ items, const int* __restrict__ nitems,
    float* __restrict__ ctx)
{
  __shared__ float qs_all[4][32 * 64];
  __shared__ float sa_all[4][64];
  const int wid = threadIdx.x >> 6, lane = threadIdx.x & 63;
  const int idx = blockIdx.x * 4 + wid;
  if (idx >= nitems[0]) return;          // wave-uniform exit
  const int4 it = items[idx];
  const int code = it.x, qstart = it.y, qn = it.z, cnt = it.w;
  const int bh = code >> 4;
  float* qs = qs_all[wid];
  float* sa = sa_all[wid];

  const float* qbh = qb + (size_t)bh * Ll * DKq;
  const float* kbh = kb + (size_t)bh * Ll * DKq;
  const float* vbh = vb + (size_t)bh * Ll * DKq;

  int qidx_v = (lane < qn)  ? qlist[bh * Ll + qstart + lane] : 0;
  int cidx_v = (lane < cnt) ? kcand[(size_t)code * KMAX + lane] : 0;

  float4 kr[16];
  {
    const float4* krow = (const float4*)kbh + (size_t)cidx_v * 16;
    #pragma unroll
    for (int i = 0; i < 16; i++) kr[i] = krow[i];
  }
  float vt[64];
  #pragma unroll
  for (int c = 0; c < 64; c++) {
    int rowc = __shfl(cidx_v, c);
    vt[c] = vbh[(size_t)rowc * DKq + lane];
  }
  #pragma unroll
  for (int i = 0; i < 8; i++) {
    int f = lane + 64 * i;
    int r = f >> 4, c4 = f & 15;
    int qrow = __shfl(qidx_v, r);
    float4 qv = *((const float4*)qbh + (size_t)qrow * 16 + c4);
    *(float4*)&qs[r * 64 + c4 * 4] = qv;
  }
  lds_fence();

  const int b = bh >> 3, h = bh & 7;
  const float4* qs4 = (const float4*)qs;
  const float4* sa4 = (const float4*)sa;

  for (int j = 0; j < qn; j++) {
    float s0 = 0.f, s1 = 0.f, s2 = 0.f, s3 = 0.f;
    #pragma unroll
    for (int i = 0; i < 16; i += 4) {
      float4 q0 = qs4[j * 16 + i + 0];
      float4 q1 = qs4[j * 16 + i + 1];
      float4 q2 = qs4[j * 16 + i + 2];
      float4 q3 = qs4[j * 16 + i + 3];
      s0 += q0.x*kr[i+0].x + q0.y*kr[i+0].y + q0.z*kr[i+0].z + q0.w*kr[i+0].w;
      s1 += q1.x*kr[i+1].x + q1.y*kr[i+1].y + q1.z*kr[i+1].z + q1.w*kr[i+1].w;
      s2 += q2.x*kr[i+2].x + q2.y*kr[i+2].y + q2.z*kr[i+2].z + q2.w*kr[i+2].w;
      s3 += q3.x*kr[i+3].x + q3.y*kr[i+3].y + q3.z*kr[i+3].z + q3.w*kr[i+3].w;
    }
    float s = ((s0 + s1) + (s2 + s3)) * 0.125f;
    s = (lane < cnt) ? s : -INFINITY;
    float m = s;
    #pragma unroll
    for (int off = 32; off; off >>= 1) m = fmaxf(m, __shfl_xor(m, off));
    float e = __expf(s - m);
    float sum = e;
    #pragma unroll
    for (int off = 32; off; off >>= 1) sum += __shfl_xor(sum, off);
    lds_fence();
    sa[lane] = e;
    lds_fence();
    float c0 = 0.f, c1 = 0.f, c2 = 0.f, c3 = 0.f;
    #pragma unroll
    for (int i = 0; i < 16; i++) {
      float4 a = sa4[i];
      c0 += a.x * vt[4*i + 0];
      c1 += a.y * vt[4*i + 1];
      c2 += a.z * vt[4*i + 2];
      c3 += a.w * vt[4*i + 3];
    }
    float ctxd = ((c0 + c1) + (c2 + c3)) / sum;
    int qrow = __shfl(qidx_v, j);
    ctx[((size_t)(b * Ll + qrow)) * 512 + h * 64 + lane] = ctxd;
  }
}

// ---------------------------------------------------------------------------
// T[h,dk,n] = sum_r U[h,dk,r] * V[h,r,n]  (unchanged)
// ---------------------------------------------------------------------------
__global__ __launch_bounds__(256) void uv_kernel(
    const float* __restrict__ U, const float* __restrict__ V, float* __restrict__ T)
{
  int idx = blockIdx.x * 256 + threadIdx.x;
  int n = idx & 511, dk = (idx >> 9) & 63, h = idx >> 15;
  float acc = 0.f;
  #pragma unroll
  for (int r = 0; r < 32; r++)
    acc += U[((size_t)h * 64 + dk) * 32 + r] * V[((size_t)h * 32 + r) * 512 + n];
  T[idx] = acc;
}

// ---------------------------------------------------------------------------
// Mf[h*64+dk, n] = sum_c T[h,dk,c] * Wo[h*512+c, n].  (unchanged)
// ---------------------------------------------------------------------------
__global__ __launch_bounds__(256) void m_kernel(
    const float* __restrict__ T, const float* __restrict__ Wo, float* __restrict__ Mf)
{
  __shared__ float Ts[16][68];
  __shared__ float Ws[16][68];
  const int h = blockIdx.y;
  const int n0 = blockIdx.x * 64;
  const int tid = threadIdx.x;
  const int tx = tid & 15, ty = tid >> 4;
  float acc[4][4] = {};
  for (int k0 = 0; k0 < 512; k0 += 16) {
    {
      int r = tid >> 2, cg = (tid & 3) << 2;
      float4 a = *(const float4*)&T[((size_t)(h*64 + r))*512 + k0 + cg];
      Ts[cg+0][r]=a.x; Ts[cg+1][r]=a.y; Ts[cg+2][r]=a.z; Ts[cg+3][r]=a.w;
    }
    {
      int row = tid >> 4, c4 = tid & 15;
      *(float4*)&Ws[row][c4*4] = *(const float4*)&Wo[((size_t)(h*512 + k0 + row))*512 + n0 + c4*4];
    }
    __syncthreads();
    #pragma unroll
    for (int kk = 0; kk < 16; kk++) {
      float4 a0 = *(const float4*)&Ts[kk][ty*4];
      float4 b0 = *(const float4*)&Ws[kk][tx*4];
      float av[4] = {a0.x,a0.y,a0.z,a0.w};
      float bw[4] = {b0.x,b0.y,b0.z,b0.w};
      #pragma unroll
      for (int i=0;i<4;i++)
        #pragma unroll
        for (int j=0;j<4;j++) acc[i][j] += av[i]*bw[j];
    }
    __syncthreads();
  }
  #pragma unroll
  for (int i=0;i<4;i++) {
    int row = h*64 + ty*4 + i;
    #pragma unroll
    for (int j=0;j<4;j++)
      Mf[(size_t)row * 512 + n0 + tx*4 + j] = acc[i][j];
  }
}

// ---------------------------------------------------------------------------
// OUT(4096x512) = CTX @ Mf + bo.  (unchanged from round 7/8)
// ---------------------------------------------------------------------------
__global__ __launch_bounds__(128) void out_gemm(
    const float* __restrict__ A, const float* __restrict__ Bm,
    const float* __restrict__ bias, float* __restrict__ C)
{
  __shared__ float As[32][68];
  __shared__ float Bs[32][68];
  const int tid = threadIdx.x;
  const int m0 = blockIdx.y * 64, n0 = blockIdx.x * 64;
  const int tx = tid & 15, ty = tid >> 4;

  float4 ar[4], br[4];
  #pragma unroll
  for (int i = 0; i < 4; i++) {
    int g = i * 128 + tid, row = g >> 3, c4 = g & 7;
    ar[i] = *(const float4*)&A[(size_t)(m0 + row) * 512 + c4 * 4];
  }
  #pragma unroll
  for (int i = 0; i < 4; i++) {
    int g = i * 128 + tid, row = g >> 4, c4 = g & 15;
    br[i] = *(const float4*)&Bm[(size_t)row * 512 + n0 + c4 * 4];
  }

  float acc[8][4] = {};
  for (int k0 = 0; k0 < 512; k0 += 32) {
    __syncthreads();
    #pragma unroll
    for (int i = 0; i < 4; i++) {
      int g = i * 128 + tid, row = g >> 3, c4 = g & 7;
      int mswz = ((c4 >> 1) & 1) << 3;
      As[c4*4+0][(row ^ mswz)] = ar[i].x;
      As[c4*4+1][(row ^ mswz)] = ar[i].y;
      As[c4*4+2][(row ^ mswz)] = ar[i].z;
      As[c4*4+3][(row ^ mswz)] = ar[i].w;
    }
    #pragma unroll
    for (int i = 0; i < 4; i++) {
      int g = i * 128 + tid, row = g >> 4, c4 = g & 15;
      *(float4*)&Bs[row][c4*4] = br[i];
    }
    __syncthreads();
    if (k0 + 32 < 512) {
      #pragma unroll
      for (int i = 0; i < 4; i++) {
        int g = i * 128 + tid, row = g >> 3, c4 = g & 7;
        ar[i] = *(const float4*)&A[(size_t)(m0 + row) * 512 + (k0 + 32) + c4 * 4];
      }
      #pragma unroll
      for (int i = 0; i < 4; i++) {
        int g = i * 128 + tid, row = g >> 4, c4 = g & 15;
        br[i] = *(const float4*)&Bm[(size_t)(k0 + 32 + row) * 512 + n0 + c4 * 4];
      }
    }
    #pragma unroll
    for (int kk = 0; kk < 32; kk++) {
      const int mswz = ((kk >> 3) & 1) << 3;
      const int mb = (ty * 8) ^ mswz;
      float4 a0 = *(const float4*)&As[kk][mb];
      float4 a1 = *(const float4*)&As[kk][mb + 4];
      float4 b0 = *(const float4*)&Bs[kk][tx*4];
      float av[8] = {a0.x,a0.y,a0.z,a0.w,a1.x,a1.y,a1.z,a1.w};
      float bw[4] = {b0.x,b0.y,b0.z,b0.w};
      #pragma unroll
      for (int i=0;i<8;i++)
        #pragma unroll
        for (int j=0;j<4;j++) acc[i][j] += av[i]*bw[j];
    }
  }
  #pragma unroll
  for (int i=0;i<8;i++) {
    int m = m0 + ty*8 + i;
    #pragma unroll
    for (int j=0;j<4;j++) {
      int n = n0 + tx*4 + j;
      C[(size_t)m * 512 + n] = acc[i][j] + bias[n];
    }
  }
}

// ---------------------------------------------------------------------------
extern "C" void kernel_launch(void* const* d_in, const int* in_sizes, int n_in,
                              void* d_out, int out_size, void* d_ws, size_t ws_size,
                              hipStream_t stream)
{
  const float* query = (const float*)d_in[0];
  const float* key   = (const float*)d_in[1];
  const float* value = (const float*)d_in[2];
  const float* Wq = (const float*)d_in[3];
  const float* bq = (const float*)d_in[4];
  const float* Wk = (const float*)d_in[5];
  const float* bk = (const float*)d_in[6];
  const float* Wv = (const float*)d_in[7];
  const float* bv = (const float*)d_in[8];
  const float* U  = (const float*)d_in[9];
  const float* V  = (const float*)d_in[10];
  const float* rv = (const float*)d_in[11];
  const float* Wo = (const float*)d_in[12];
  const float* bo = (const float*)d_in[13];
  float* out = (float*)d_out;

  float* ws = (float*)d_ws;
  const size_t NQKV = (size_t)Bb * Hh * Ll * DKq;
  float* qb   = ws;
  float* kb   = qb + NQKV;
  float* vb   = kb + NQKV;
  float* ctx  = vb + NQKV;
  float* T    = ctx + NQKV;
  float* Mf   = T + (size_t)Hh * DKq * 512;
  int* qhash  = (int*)(Mf + 512 * 512);
  int* khash  = qhash + Bb * Hh * Ll;
  int* kcand  = khash + Bb * Hh * Ll;
  int* kcount = kcand + Bb * Hh * NBUCK * KMAX;
  int* qoff   = kcount + Bb * Hh * NBUCK;
  int* qlist  = qoff + Bb * Hh * (NBUCK + 1);
  int4* items = (int4*)(qlist + Bb * Hh * Ll);    // 16B-aligned offset
  int* nitems = (int*)(items + MAX_ITEMS);

  proj_kernel<<<dim3(4, 64, 3), 128, 0, stream>>>(query, key, value,
                                                  Wq, Wk, Wv, bq, bk, bv,
                                                  qb, kb, vb);
  hash_kernel<<<(2 * Bb * Hh * Ll * 64) / 256, 256, 0, stream>>>(qb, kb, rv, qhash, khash);
  kcand_kernel<<<Bb * Hh * NBUCK, 64, 0, stream>>>(khash, kcand, kcount);
  qlist_kernel<<<Bb * Hh, 256, 0, stream>>>(qhash, qoff, qlist);
  worklist_kernel<<<1, 256, 0, stream>>>(qoff, kcount, items, nitems);
  attn_kernel<<<MAX_ITEMS / 4, 256, 0, stream>>>(qb, kb, vb, qlist, kcand,
                                                 items, nitems, ctx);
  uv_kernel<<<(Hh * DKq * 512) / 256, 256, 0, stream>>>(U, V, T);
  m_kernel<<<dim3(8, 8), 256, 0, stream>>>(T, Wo, Mf);
  out_gemm<<<dim3(8, 64), 128, 0, stream>>>(ctx, Mf, bo, out);
}

// Round 10
// 262.046 us; speedup vs baseline: 1.1018x; 1.1018x over previous
//
#include <hip/hip_runtime.h>
#include <math.h>

// Problem constants (from reference)
#define Bb 2
#define Ll 2048
#define Dd 512
#define Hh 8
#define DKq 64
#define NBUCK 16
#define KMAX 64
#define MAX_ITEMS 1280   // exact bound: 16 bh * (64 + 16) chunks of 32

// ---------------------------------------------------------------------------
// Direct global->LDS DMA (gfx950), 16B per lane.  LDS dest = uniform base +
// lane*16 (linear); per-lane GLOBAL address may carry a swizzle (m173/m201).
// ---------------------------------------------------------------------------
__device__ __forceinline__ void gl_lds16(const float* g, float* l) {
  __builtin_amdgcn_global_load_lds(
      (const __attribute__((address_space(1))) void*)g,
      (__attribute__((address_space(3))) void*)l, 16, 0, 0);
}

// Counted-vmcnt barrier (T4): wait until <= N staging loads outstanding,
// then raw s_barrier -- newer tiles' loads stay in flight ACROSS the
// barrier (never drain to 0 in steady state).  "memory" clobber orders all
// LDS/global accesses; sched_barrier pins the scheduler (rule #18).
#define VM_BARRIER(N)                                             \
  do {                                                            \
    asm volatile("s_waitcnt vmcnt(" #N ")\n\ts_barrier" ::: "memory"); \
    __builtin_amdgcn_sched_barrier(0);                            \
  } while (0)

// ---------------------------------------------------------------------------
// Projection GEMM: X(4096x512) @ W(512x512) + b -> (b,h,l,dk) scatter.
// 128 thr, BM=64 BN=128 BK=16, 8x8 microtile, grid (4,64,3)=768 = 3/CU.
// T3+T4 schedule: 4-deep LDS multibuffer (12 KB/buf, 48 KB total), staging
// via global_load_lds, per-tile sync = s_waitcnt vmcnt(12) + raw s_barrier
// (tiles t+1,t+2 in flight across every barrier; 12 -> 6 -> 0 at the tail).
// 4-buffer depth proof: issue(t+2) at iter t overwrites buf[(t+2)&3], last
// read by compute(t-2); every wave has passed barrier(t-1) > compute(t-2).
// Per-output FMA chain is ascending-k, one fma per k -> bit-identical q/k
// across rounds (LSH sign-critical).  Do not alter math/accumulation order.
// ---------------------------------------------------------------------------
__global__ __launch_bounds__(128) void proj_kernel(
    const float* __restrict__ Xq, const float* __restrict__ Xk, const float* __restrict__ Xv,
    const float* __restrict__ Wq, const float* __restrict__ Wk, const float* __restrict__ Wv,
    const float* __restrict__ bq, const float* __restrict__ bk, const float* __restrict__ bv,
    float* __restrict__ qb, float* __restrict__ kb, float* __restrict__ vb)
{
  const float *X, *W, *bias; float* dst;
  if (blockIdx.z == 0)      { X=Xq; W=Wq; bias=bq; dst=qb; }
  else if (blockIdx.z == 1) { X=Xk; W=Wk; bias=bk; dst=kb; }
  else                      { X=Xv; W=Wv; bias=bv; dst=vb; }
  __shared__ float As[4][64 * 16];    // [buf][m][k]   4 KB each
  __shared__ float Bs[4][16 * 128];   // [buf][k][n]   8 KB each
  const int tid = threadIdx.x;
  const int m0 = blockIdx.y * 64;
  const int n0 = blockIdx.x * 128;
  const int tx = tid & 15, ty = tid >> 4;      // 16 x 8 thread grid
  const int lane = tid & 63, wid = tid >> 6;   // 2 waves

  // Per-lane global source pointers for the DMA (linear, no swizzle).
  const float* aSrc[2];
  #pragma unroll
  for (int j = 0; j < 2; j++) {
    int jj = wid * 2 + j;                      // 16 rows per instruction
    aSrc[j] = X + (size_t)(m0 + 16*jj + (lane >> 2)) * 512 + ((lane & 3) << 2);
  }
  const float* bSrc[4];
  #pragma unroll
  for (int j = 0; j < 4; j++) {
    int jj = wid * 4 + j;                      // 2 k-rows per instruction
    bSrc[j] = W + (size_t)(2*jj + (lane >> 5)) * 512 + n0 + ((lane & 31) << 2);
  }

  // Prologue: stage tiles 0 and 1.
  #pragma unroll
  for (int j = 0; j < 2; j++) gl_lds16(aSrc[j],                 &As[0][(wid*2+j)*256]);
  #pragma unroll
  for (int j = 0; j < 4; j++) gl_lds16(bSrc[j],                 &Bs[0][(wid*4+j)*256]);
  #pragma unroll
  for (int j = 0; j < 2; j++) gl_lds16(aSrc[j] + 16,            &As[1][(wid*2+j)*256]);
  #pragma unroll
  for (int j = 0; j < 4; j++) gl_lds16(bSrc[j] + (size_t)16*512,&Bs[1][(wid*4+j)*256]);

  float acc[8][8] = {};
  for (int t = 0; t < 32; t++) {
    const int cur = t & 3;
    if (t < 30) {                               // stage tile t+2
      const int k0 = (t + 2) * 16;
      const int nb = (t + 2) & 3;
      #pragma unroll
      for (int j = 0; j < 2; j++) gl_lds16(aSrc[j] + k0,              &As[nb][(wid*2+j)*256]);
      #pragma unroll
      for (int j = 0; j < 4; j++) gl_lds16(bSrc[j] + (size_t)k0*512,  &Bs[nb][(wid*4+j)*256]);
    }
    // Counted wait: tile t's 6 loads complete; t+1/t+2's 12 may remain.
    if (t < 30)      VM_BARRIER(12);
    else if (t == 30) VM_BARRIER(6);
    else              VM_BARRIER(0);

    const float* Ac = &As[cur][0];
    const float* Bc = &Bs[cur][0];
    #pragma unroll
    for (int kk4 = 0; kk4 < 4; kk4++) {
      float4 a[8];
      #pragma unroll
      for (int i = 0; i < 8; i++)
        a[i] = *(const float4*)&Ac[(ty*8 + i)*16 + (kk4 << 2)];
      #pragma unroll
      for (int s = 0; s < 4; s++) {
        const int kk = kk4*4 + s;
        float4 b0 = *(const float4*)&Bc[kk*128 + tx*4];
        float4 b1 = *(const float4*)&Bc[kk*128 + 64 + tx*4];
        #pragma unroll
        for (int i = 0; i < 8; i++) {
          const float as = (s==0) ? a[i].x : (s==1) ? a[i].y : (s==2) ? a[i].z : a[i].w;
          acc[i][0] += as * b0.x;  acc[i][1] += as * b0.y;
          acc[i][2] += as * b0.z;  acc[i][3] += as * b0.w;
          acc[i][4] += as * b1.x;  acc[i][5] += as * b1.y;
          acc[i][6] += as * b1.z;  acc[i][7] += as * b1.w;
        }
      }
    }
    // Reads of buf[cur] finish before the NEXT iteration's barrier lets any
    // wave overwrite it (4-deep: overwrite happens 4 tiles later).
  }

  const int head0 = n0 >> 6;           // two 64-col heads per tile
  const int d0 = tx * 4;
  #pragma unroll
  for (int i = 0; i < 8; i++) {
    int m = m0 + ty*8 + i;
    int b = m >> 11, l = m & 2047;
    float* drow0 = &dst[(((size_t)b*Hh + head0)*Ll + l)*DKq];
    float* drow1 = &dst[(((size_t)b*Hh + head0 + 1)*Ll + l)*DKq];
    #pragma unroll
    for (int j = 0; j < 4; j++) drow0[d0 + j] = acc[i][j]   + bias[n0 + tx*4 + j];
    #pragma unroll
    for (int j = 0; j < 4; j++) drow1[d0 + j] = acc[i][4+j] + bias[n0 + 64 + tx*4 + j];
  }
}

// ---------------------------------------------------------------------------
// LSH hash (unchanged)
// ---------------------------------------------------------------------------
__global__ __launch_bounds__(256) void hash_kernel(
    const float* __restrict__ qb, const float* __restrict__ kb,
    const float* __restrict__ rv, int* __restrict__ qhash, int* __restrict__ khash)
{
  int gwave = (blockIdx.x * blockDim.x + threadIdx.x) >> 6;
  int lane = threadIdx.x & 63;
  const int NR = Bb * Hh * Ll;
  if (gwave >= 2 * NR) return;
  int isK = gwave >= NR;
  int row = isK ? gwave - NR : gwave;
  int h = (row >> 11) & 7;
  const float* src = isK ? kb : qb;
  float x = src[(size_t)row * DKq + lane];
  float r = rv[h * DKq + lane];
  float v = (x > 0.0f) ? r : 0.0f;
  #pragma unroll
  for (int off = 32; off; off >>= 1) v += __shfl_xor(v, off);
  if (lane == 0) {
    float fb = floorf(v * 0.125f);
    int ib = (int)fb;
    int bucket = ib & 15;
    (isK ? khash : qhash)[row] = bucket;
  }
}

// ---------------------------------------------------------------------------
// First <=64 ascending key indices per (b,h,bucket) (unchanged)
// ---------------------------------------------------------------------------
__global__ __launch_bounds__(64) void kcand_kernel(
    const int* __restrict__ khash, int* __restrict__ kcand, int* __restrict__ kcount)
{
  int bh = blockIdx.x >> 4;
  int bucket = blockIdx.x & 15;
  int lane = threadIdx.x;
  const int* kh = &khash[bh * Ll];
  int* cl = &kcand[(size_t)blockIdx.x * KMAX];
  int total = 0;
  for (int c0 = 0; c0 < Ll && total < KMAX; c0 += 64) {
    int hv = kh[c0 + lane];
    unsigned long long m = __ballot(hv == bucket);
    int pre = __popcll(m & ((1ULL << lane) - 1ULL));
    if (hv == bucket && total + pre < KMAX) cl[total + pre] = c0 + lane;
    total += __popcll(m);
  }
  if (lane == 0) kcount[blockIdx.x] = total < KMAX ? total : KMAX;
}

// ---------------------------------------------------------------------------
// Group queries by bucket per (b,h) (unchanged)
// ---------------------------------------------------------------------------
__global__ __launch_bounds__(256) void qlist_kernel(
    const int* __restrict__ qhash, int* __restrict__ qoff, int* __restrict__ qlist)
{
  int bh = blockIdx.x;
  __shared__ int cnt[NBUCK], cur[NBUCK], off[NBUCK + 1];
  if (threadIdx.x < NBUCK) cnt[threadIdx.x] = 0;
  __syncthreads();
  const int* qh = &qhash[bh * Ll];
  for (int l = threadIdx.x; l < Ll; l += 256) atomicAdd(&cnt[qh[l]], 1);
  __syncthreads();
  if (threadIdx.x == 0) {
    int s = 0;
    for (int i = 0; i < NBUCK; i++) { off[i] = s; cur[i] = s; s += cnt[i]; }
    off[NBUCK] = s;
  }
  __syncthreads();
  if (threadIdx.x < NBUCK + 1) qoff[bh * (NBUCK + 1) + threadIdx.x] = off[threadIdx.x];
  for (int l = threadIdx.x; l < Ll; l += 256) {
    int p = atomicAdd(&cur[qh[l]], 1);
    qlist[bh * Ll + p] = l;
  }
}

// ---------------------------------------------------------------------------
// Deterministic worklist: one item per active (bh,bucket,chunk-of-32-queries).
// ---------------------------------------------------------------------------
__global__ __launch_bounds__(256) void worklist_kernel(
    const int* __restrict__ qoff, const int* __restrict__ kcount,
    int4* __restrict__ items, int* __restrict__ nitems)
{
  int t = threadIdx.x;
  int bh = t >> 4, bucket = t & 15;
  int o0 = qoff[bh * 17 + bucket], o1 = qoff[bh * 17 + bucket + 1];
  int cnt = kcount[t];
  int nq = o1 - o0;
  int n = (cnt > 0) ? ((nq + 31) >> 5) : 0;
  __shared__ int sc[256];
  sc[t] = n;
  __syncthreads();
  for (int off = 1; off < 256; off <<= 1) {
    int v = (t >= off) ? sc[t - off] : 0;
    __syncthreads();
    sc[t] += v;
    __syncthreads();
  }
  int start = sc[t] - n;
  for (int i = 0; i < n; i++) {
    int q0 = 32 * i;
    int qn = nq - q0; if (qn > 32) qn = 32;
    items[start + i] = make_int4(t, o0 + q0, qn, cnt);
  }
  if (t == 255) nitems[0] = sc[255];
}

// ---------------------------------------------------------------------------
// LDS fence for same-wave cross-lane LDS dependences (rule #18).
// ---------------------------------------------------------------------------
__device__ __forceinline__ void lds_fence() {
  asm volatile("s_waitcnt lgkmcnt(0)" ::: "memory");
  __builtin_amdgcn_sched_barrier(0);
}

// ---------------------------------------------------------------------------
// Attention: one WAVE per item (<=32 q x <=64 cand x 64 dim).  K rows in
// regs (lane=c), V^T in regs (lane=d), Q via wave-private LDS broadcasts.
// (unchanged -- correctness-verified rounds 4/6/7/8/9)
// ---------------------------------------------------------------------------
__global__ __launch_bounds__(256, 2) void attn_kernel(
    const float* __restrict__ qb, const float* __restrict__ kb, const float* __restrict__ vb,
    const int* __restrict__ qlist, const int* __restrict__ kcand,
    const int4* __restrict__ items, const int* __restrict__ nitems,
    float* __restrict__ ctx)
{
  __shared__ float qs_all[4][32 * 64];
  __shared__ float sa_all[4][64];
  const int wid = threadIdx.x >> 6, lane = threadIdx.x & 63;
  const int idx = blockIdx.x * 4 + wid;
  if (idx >= nitems[0]) return;          // wave-uniform exit
  const int4 it = items[idx];
  const int code = it.x, qstart = it.y, qn = it.z, cnt = it.w;
  const int bh = code >> 4;
  float* qs = qs_all[wid];
  float* sa = sa_all[wid];

  const float* qbh = qb + (size_t)bh * Ll * DKq;
  const float* kbh = kb + (size_t)bh * Ll * DKq;
  const float* vbh = vb + (size_t)bh * Ll * DKq;

  int qidx_v = (lane < qn)  ? qlist[bh * Ll + qstart + lane] : 0;
  int cidx_v = (lane < cnt) ? kcand[(size_t)code * KMAX + lane] : 0;

  float4 kr[16];
  {
    const float4* krow = (const float4*)kbh + (size_t)cidx_v * 16;
    #pragma unroll
    for (int i = 0; i < 16; i++) kr[i] = krow[i];
  }
  float vt[64];
  #pragma unroll
  for (int c = 0; c < 64; c++) {
    int rowc = __shfl(cidx_v, c);
    vt[c] = vbh[(size_t)rowc * DKq + lane];
  }
  #pragma unroll
  for (int i = 0; i < 8; i++) {
    int f = lane + 64 * i;
    int r = f >> 4, c4 = f & 15;
    int qrow = __shfl(qidx_v, r);
    float4 qv = *((const float4*)qbh + (size_t)qrow * 16 + c4);
    *(float4*)&qs[r * 64 + c4 * 4] = qv;
  }
  lds_fence();

  const int b = bh >> 3, h = bh & 7;
  const float4* qs4 = (const float4*)qs;
  const float4* sa4 = (const float4*)sa;

  for (int j = 0; j < qn; j++) {
    float s0 = 0.f, s1 = 0.f, s2 = 0.f, s3 = 0.f;
    #pragma unroll
    for (int i = 0; i < 16; i += 4) {
      float4 q0 = qs4[j * 16 + i + 0];
      float4 q1 = qs4[j * 16 + i + 1];
      float4 q2 = qs4[j * 16 + i + 2];
      float4 q3 = qs4[j * 16 + i + 3];
      s0 += q0.x*kr[i+0].x + q0.y*kr[i+0].y + q0.z*kr[i+0].z + q0.w*kr[i+0].w;
      s1 += q1.x*kr[i+1].x + q1.y*kr[i+1].y + q1.z*kr[i+1].z + q1.w*kr[i+1].w;
      s2 += q2.x*kr[i+2].x + q2.y*kr[i+2].y + q2.z*kr[i+2].z + q2.w*kr[i+2].w;
      s3 += q3.x*kr[i+3].x + q3.y*kr[i+3].y + q3.z*kr[i+3].z + q3.w*kr[i+3].w;
    }
    float s = ((s0 + s1) + (s2 + s3)) * 0.125f;
    s = (lane < cnt) ? s : -INFINITY;
    float m = s;
    #pragma unroll
    for (int off = 32; off; off >>= 1) m = fmaxf(m, __shfl_xor(m, off));
    float e = __expf(s - m);
    float sum = e;
    #pragma unroll
    for (int off = 32; off; off >>= 1) sum += __shfl_xor(sum, off);
    lds_fence();
    sa[lane] = e;
    lds_fence();
    float c0 = 0.f, c1 = 0.f, c2 = 0.f, c3 = 0.f;
    #pragma unroll
    for (int i = 0; i < 16; i++) {
      float4 a = sa4[i];
      c0 += a.x * vt[4*i + 0];
      c1 += a.y * vt[4*i + 1];
      c2 += a.z * vt[4*i + 2];
      c3 += a.w * vt[4*i + 3];
    }
    float ctxd = ((c0 + c1) + (c2 + c3)) / sum;
    int qrow = __shfl(qidx_v, j);
    ctx[((size_t)(b * Ll + qrow)) * 512 + h * 64 + lane] = ctxd;
  }
}

// ---------------------------------------------------------------------------
// T[h,dk,n] = sum_r U[h,dk,r] * V[h,r,n]  (unchanged)
// ---------------------------------------------------------------------------
__global__ __launch_bounds__(256) void uv_kernel(
    const float* __restrict__ U, const float* __restrict__ V, float* __restrict__ T)
{
  int idx = blockIdx.x * 256 + threadIdx.x;
  int n = idx & 511, dk = (idx >> 9) & 63, h = idx >> 15;
  float acc = 0.f;
  #pragma unroll
  for (int r = 0; r < 32; r++)
    acc += U[((size_t)h * 64 + dk) * 32 + r] * V[((size_t)h * 32 + r) * 512 + n];
  T[idx] = acc;
}

// ---------------------------------------------------------------------------
// Mf[h*64+dk, n] = sum_c T[h,dk,c] * Wo[h*512+c, n].  (unchanged)
// ---------------------------------------------------------------------------
__global__ __launch_bounds__(256) void m_kernel(
    const float* __restrict__ T, const float* __restrict__ Wo, float* __restrict__ Mf)
{
  __shared__ float Ts[16][68];
  __shared__ float Ws[16][68];
  const int h = blockIdx.y;
  const int n0 = blockIdx.x * 64;
  const int tid = threadIdx.x;
  const int tx = tid & 15, ty = tid >> 4;
  float acc[4][4] = {};
  for (int k0 = 0; k0 < 512; k0 += 16) {
    {
      int r = tid >> 2, cg = (tid & 3) << 2;
      float4 a = *(const float4*)&T[((size_t)(h*64 + r))*512 + k0 + cg];
      Ts[cg+0][r]=a.x; Ts[cg+1][r]=a.y; Ts[cg+2][r]=a.z; Ts[cg+3][r]=a.w;
    }
    {
      int row = tid >> 4, c4 = tid & 15;
      *(float4*)&Ws[row][c4*4] = *(const float4*)&Wo[((size_t)(h*512 + k0 + row))*512 + n0 + c4*4];
    }
    __syncthreads();
    #pragma unroll
    for (int kk = 0; kk < 16; kk++) {
      float4 a0 = *(const float4*)&Ts[kk][ty*4];
      float4 b0 = *(const float4*)&Ws[kk][tx*4];
      float av[4] = {a0.x,a0.y,a0.z,a0.w};
      float bw[4] = {b0.x,b0.y,b0.z,b0.w};
      #pragma unroll
      for (int i=0;i<4;i++)
        #pragma unroll
        for (int j=0;j<4;j++) acc[i][j] += av[i]*bw[j];
    }
    __syncthreads();
  }
  #pragma unroll
  for (int i=0;i<4;i++) {
    int row = h*64 + ty*4 + i;
    #pragma unroll
    for (int j=0;j<4;j++)
      Mf[(size_t)row * 512 + n0 + tx*4 + j] = acc[i][j];
  }
}

// ---------------------------------------------------------------------------
// OUT(4096x512) = CTX @ Mf + bo.  (unchanged from rounds 7-9)
// ---------------------------------------------------------------------------
__global__ __launch_bounds__(128) void out_gemm(
    const float* __restrict__ A, const float* __restrict__ Bm,
    const float* __restrict__ bias, float* __restrict__ C)
{
  __shared__ float As[32][68];
  __shared__ float Bs[32][68];
  const int tid = threadIdx.x;
  const int m0 = blockIdx.y * 64, n0 = blockIdx.x * 64;
  const int tx = tid & 15, ty = tid >> 4;

  float4 ar[4], br[4];
  #pragma unroll
  for (int i = 0; i < 4; i++) {
    int g = i * 128 + tid, row = g >> 3, c4 = g & 7;
    ar[i] = *(const float4*)&A[(size_t)(m0 + row) * 512 + c4 * 4];
  }
  #pragma unroll
  for (int i = 0; i < 4; i++) {
    int g = i * 128 + tid, row = g >> 4, c4 = g & 15;
    br[i] = *(const float4*)&Bm[(size_t)row * 512 + n0 + c4 * 4];
  }

  float acc[8][4] = {};
  for (int k0 = 0; k0 < 512; k0 += 32) {
    __syncthreads();
    #pragma unroll
    for (int i = 0; i < 4; i++) {
      int g = i * 128 + tid, row = g >> 3, c4 = g & 7;
      int mswz = ((c4 >> 1) & 1) << 3;
      As[c4*4+0][(row ^ mswz)] = ar[i].x;
      As[c4*4+1][(row ^ mswz)] = ar[i].y;
      As[c4*4+2][(row ^ mswz)] = ar[i].z;
      As[c4*4+3][(row ^ mswz)] = ar[i].w;
    }
    #pragma unroll
    for (int i = 0; i < 4; i++) {
      int g = i * 128 + tid, row = g >> 4, c4 = g & 15;
      *(float4*)&Bs[row][c4*4] = br[i];
    }
    __syncthreads();
    if (k0 + 32 < 512) {
      #pragma unroll
      for (int i = 0; i < 4; i++) {
        int g = i * 128 + tid, row = g >> 3, c4 = g & 7;
        ar[i] = *(const float4*)&A[(size_t)(m0 + row) * 512 + (k0 + 32) + c4 * 4];
      }
      #pragma unroll
      for (int i = 0; i < 4; i++) {
        int g = i * 128 + tid, row = g >> 4, c4 = g & 15;
        br[i] = *(const float4*)&Bm[(size_t)(k0 + 32 + row) * 512 + n0 + c4 * 4];
      }
    }
    #pragma unroll
    for (int kk = 0; kk < 32; kk++) {
      const int mswz = ((kk >> 3) & 1) << 3;
      const int mb = (ty * 8) ^ mswz;
      float4 a0 = *(const float4*)&As[kk][mb];
      float4 a1 = *(const float4*)&As[kk][mb + 4];
      float4 b0 = *(const float4*)&Bs[kk][tx*4];
      float av[8] = {a0.x,a0.y,a0.z,a0.w,a1.x,a1.y,a1.z,a1.w};
      float bw[4] = {b0.x,b0.y,b0.z,b0.w};
      #pragma unroll
      for (int i=0;i<8;i++)
        #pragma unroll
        for (int j=0;j<4;j++) acc[i][j] += av[i]*bw[j];
    }
  }
  #pragma unroll
  for (int i=0;i<8;i++) {
    int m = m0 + ty*8 + i;
    #pragma unroll
    for (int j=0;j<4;j++) {
      int n = n0 + tx*4 + j;
      C[(size_t)m * 512 + n] = acc[i][j] + bias[n];
    }
  }
}

// ---------------------------------------------------------------------------
extern "C" void kernel_launch(void* const* d_in, const int* in_sizes, int n_in,
                              void* d_out, int out_size, void* d_ws, size_t ws_size,
                              hipStream_t stream)
{
  const float* query = (const float*)d_in[0];
  const float* key   = (const float*)d_in[1];
  const float* value = (const float*)d_in[2];
  const float* Wq = (const float*)d_in[3];
  const float* bq = (const float*)d_in[4];
  const float* Wk = (const float*)d_in[5];
  const float* bk = (const float*)d_in[6];
  const float* Wv = (const float*)d_in[7];
  const float* bv = (const float*)d_in[8];
  const float* U  = (const float*)d_in[9];
  const float* V  = (const float*)d_in[10];
  const float* rv = (const float*)d_in[11];
  const float* Wo = (const float*)d_in[12];
  const float* bo = (const float*)d_in[13];
  float* out = (float*)d_out;

  float* ws = (float*)d_ws;
  const size_t NQKV = (size_t)Bb * Hh * Ll * DKq;
  float* qb   = ws;
  float* kb   = qb + NQKV;
  float* vb   = kb + NQKV;
  float* ctx  = vb + NQKV;
  float* T    = ctx + NQKV;
  float* Mf   = T + (size_t)Hh * DKq * 512;
  int* qhash  = (int*)(Mf + 512 * 512);
  int* khash  = qhash + Bb * Hh * Ll;
  int* kcand  = khash + Bb * Hh * Ll;
  int* kcount = kcand + Bb * Hh * NBUCK * KMAX;
  int* qoff   = kcount + Bb * Hh * NBUCK;
  int* qlist  = qoff + Bb * Hh * (NBUCK + 1);
  int4* items = (int4*)(qlist + Bb * Hh * Ll);    // 16B-aligned offset
  int* nitems = (int*)(items + MAX_ITEMS);

  proj_kernel<<<dim3(4, 64, 3), 128, 0, stream>>>(query, key, value,
                                                  Wq, Wk, Wv, bq, bk, bv,
                                                  qb, kb, vb);
  hash_kernel<<<(2 * Bb * Hh * Ll * 64) / 256, 256, 0, stream>>>(qb, kb, rv, qhash, khash);
  kcand_kernel<<<Bb * Hh * NBUCK, 64, 0, stream>>>(khash, kcand, kcount);
  qlist_kernel<<<Bb * Hh, 256, 0, stream>>>(qhash, qoff, qlist);
  worklist_kernel<<<1, 256, 0, stream>>>(qoff, kcount, items, nitems);
  attn_kernel<<<MAX_ITEMS / 4, 256, 0, stream>>>(qb, kb, vb, qlist, kcand,
                                                 items, nitems, ctx);
  uv_kernel<<<(Hh * DKq * 512) / 256, 256, 0, stream>>>(U, V, T);
  m_kernel<<<dim3(8, 8), 256, 0, stream>>>(T, Wo, Mf);
  out_gemm<<<dim3(8, 64), 128, 0, stream>>>(ctx, Mf, bo, out);
}